// Round 1
// baseline (330.058 us; speedup 1.0000x reference)
//
#include <hip/hip_runtime.h>
#include <math.h>

#define B_ 16
#define H_ 10
#define L_ 4096
#define S_ 77
#define D_ 64
#define NE_ 20
#define NP_ (B_*NE_)
#define SHRINK_ 2.0f

typedef __bf16 bf16x8 __attribute__((ext_vector_type(8)));
typedef float  f32x4  __attribute__((ext_vector_type(4)));

// ---------------- K1: subj scores: subj[p=i*NE+j][l] = mean_h(Q[bs,h,l,:].K[bs,h,ss,:])/8 ----
__global__ __launch_bounds__(256) void k1_subj(const float* __restrict__ Q,
                                               const float* __restrict__ K,
                                               const int* __restrict__ idxb,
                                               const int* __restrict__ idxn,
                                               float* __restrict__ subj) {
  __shared__ float Ks[NE_][640];
  __shared__ int bs[NE_], ss[NE_], s_uni;
  const int i = blockIdx.x;
  const int l = blockIdx.y * 256 + threadIdx.x;
  const int tid = threadIdx.x;
  if (tid < NE_) { bs[tid] = idxb[i*NE_ + tid]; ss[tid] = idxn[i*NE_ + tid]; }
  __syncthreads();
  if (tid == 0) { int u = 1; for (int j = 1; j < NE_; ++j) u &= (bs[j] == bs[0]); s_uni = u; }
  for (int e = tid; e < NE_*640; e += 256) {
    int j = e / 640; int hd = e - j*640; int h = hd >> 6; int d = hd & 63;
    Ks[j][hd] = K[((bs[j]*H_ + h)*S_ + ss[j])*D_ + d];
  }
  __syncthreads();
  const float sc = 1.0f / (8.0f * (float)H_);
  if (s_uni) {
    float acc[NE_];
    #pragma unroll
    for (int j = 0; j < NE_; ++j) acc[j] = 0.f;
    const int b0 = bs[0];
    for (int h = 0; h < H_; ++h) {
      const float* qb = Q + ((size_t)(b0*H_ + h)*L_ + l)*D_;
      #pragma unroll 4
      for (int d4 = 0; d4 < 16; ++d4) {
        const float4 q = *(const float4*)(qb + d4*4);
        #pragma unroll
        for (int j = 0; j < NE_; ++j) {
          const float4 k4 = *(const float4*)&Ks[j][h*64 + d4*4];
          acc[j] += q.x*k4.x + q.y*k4.y + q.z*k4.z + q.w*k4.w;
        }
      }
    }
    #pragma unroll
    for (int j = 0; j < NE_; ++j) subj[(size_t)(i*NE_ + j)*L_ + l] = acc[j]*sc;
  } else {
    // generic path: idx_b varies within a row (not hit for this dataset)
    for (int j = 0; j < NE_; ++j) {
      float a = 0.f; const int bj = bs[j];
      for (int h = 0; h < H_; ++h) {
        const float* qb = Q + ((size_t)(bj*H_ + h)*L_ + l)*D_;
        for (int d4 = 0; d4 < 16; ++d4) {
          const float4 q  = *(const float4*)(qb + d4*4);
          const float4 k4 = *(const float4*)&Ks[j][h*64 + d4*4];
          a += q.x*k4.x + q.y*k4.y + q.z*k4.z + q.w*k4.w;
        }
      }
      subj[(size_t)(i*NE_ + j)*L_ + l] = a*sc;
    }
  }
}

// ---------------- K2: per-pair softmax over L + spatial moments -> 5 params ----------------
__global__ __launch_bounds__(256) void k2_moments(const float* __restrict__ subj,
                                                  float* __restrict__ params) {
  const int p = blockIdx.x;
  const int tid = threadIdx.x;
  const int lane = tid & 63, wid = tid >> 6;
  const float* sp = subj + (size_t)p*L_;
  __shared__ float red[4];
  float m = -1e30f;
  for (int l = tid; l < L_; l += 256) m = fmaxf(m, sp[l]);
  #pragma unroll
  for (int s = 1; s < 64; s <<= 1) m = fmaxf(m, __shfl_xor(m, s, 64));
  if (lane == 0) red[wid] = m;
  __syncthreads();
  m = fmaxf(fmaxf(red[0], red[1]), fmaxf(red[2], red[3]));
  __syncthreads();
  float se = 0, sy = 0, sx = 0, syy = 0, sxx = 0;
  for (int l = tid; l < L_; l += 256) {
    float e = __expf(sp[l] - m);
    float y = (float)(l >> 6), x = (float)(l & 63);  // p3 reshape: y = l/64 (Hs axis), x = l%64
    se += e; sy += e*y; sx += e*x; syy += e*y*y; sxx += e*x*x;
  }
  float vals[5] = {se, sy, sx, syy, sxx};
  #pragma unroll
  for (int q = 0; q < 5; ++q) {
    float v = vals[q];
    #pragma unroll
    for (int s = 1; s < 64; s <<= 1) v += __shfl_xor(v, s, 64);
    if (lane == 0) red[wid] = v;
    __syncthreads();
    v = red[0] + red[1] + red[2] + red[3];
    __syncthreads();
    vals[q] = v;
  }
  if (tid == 0) {
    float xc = vals[2]/vals[0], yc = vals[1]/vals[0];
    float varx = vals[4]/vals[0] - xc*xc;
    float vary = vals[3]/vals[0] - yc*yc;
    float sh = SHRINK_ - 1.0f;
    float isx = sh*sh/(2.f*varx), isy = sh*sh/(2.f*vary);  // 1/(2 s_x^2)
    float rx = rintf(xc), ry = rintf(yc);                  // argmax over integer grid
    float mv = __expf(-((rx-xc)*(rx-xc)*isx + (ry-yc)*(ry-yc)*isy));
    params[p*8+0] = xc; params[p*8+1] = yc;
    params[p*8+2] = isx; params[p*8+3] = isy; params[p*8+4] = mv;
  }
}

// ---------------- K2b: global grid max + (b,s) -> pair map ----------------
__global__ __launch_bounds__(256) void k2b_finish(const float* __restrict__ params,
                                                  const int* __restrict__ idxb,
                                                  const int* __restrict__ idxn,
                                                  int* __restrict__ pmap,
                                                  float* __restrict__ invg) {
  const int tid = threadIdx.x;
  for (int e = tid; e < B_*S_; e += 256) pmap[e] = -1;
  __syncthreads();
  for (int p = tid; p < NP_; p += 256) pmap[idxb[p]*S_ + idxn[p]] = p;
  float m = 0.f;
  for (int p = tid; p < NP_; p += 256) m = fmaxf(m, params[p*8+4]);
  #pragma unroll
  for (int s = 1; s < 64; s <<= 1) m = fmaxf(m, __shfl_xor(m, s, 64));
  __shared__ float red[4];
  if ((tid & 63) == 0) red[tid >> 6] = m;
  __syncthreads();
  if (tid == 0) {
    m = fmaxf(fmaxf(red[0], red[1]), fmaxf(red[2], red[3]));
    invg[0] = 1.0f / m;
  }
}

// ---------------- K3: fused attention: softmax(QK^T/8) * scales @ V ----------------
__global__ __launch_bounds__(256) void k3_attn(const float* __restrict__ Q,
                                               const float* __restrict__ K,
                                               const float* __restrict__ V,
                                               const int* __restrict__ pmap,
                                               const float* __restrict__ params,
                                               const float* __restrict__ invg,
                                               float* __restrict__ out) {
  const int bh = blockIdx.y;
  const int b = bh / H_;
  const int lchunk = blockIdx.x * 256;
  const int tid = threadIdx.x, lane = tid & 63, wid = tid >> 6;
  const int col = lane & 15, grp = lane >> 4;

  __shared__ __bf16 Wl[4][16][120];   // per-wave P tile; rows padded to 120 (16B-aligned, 2-way banks)
  __shared__ float4 pp[80];
  __shared__ int pact[80];

  for (int e = tid; e < 4*16*120; e += 256) ((__bf16*)Wl)[e] = (__bf16)0.f;
  for (int s = tid; s < 80; s += 256) {
    int a = 0; float4 v = make_float4(0.f, 0.f, 0.f, 0.f);
    if (s < S_) {
      int pid = pmap[b*S_ + s];
      if (pid >= 0) {
        a = 1;
        v = make_float4(params[pid*8+0], params[pid*8+1], params[pid*8+2], params[pid*8+3]);
      }
    }
    pp[s] = v; pact[s] = a;
  }
  const float invgv = invg[0];
  __syncthreads();

  // K fragments (B-operand: col=lane&15 -> s, k=(lane>>4)*8+j -> d), hi/lo bf16 split
  bf16x8 kfh[2][5], kfl[2][5];
  #pragma unroll
  for (int ks = 0; ks < 2; ++ks) {
    #pragma unroll
    for (int n = 0; n < 5; ++n) {
      int s = col + 16*n;
      bf16x8 hi, lo;
      if (s < S_) {
        const float* kp = K + ((size_t)bh*S_ + s)*D_ + ks*32 + grp*8;
        const float4 a = *(const float4*)kp;
        const float4 c = *(const float4*)(kp + 4);
        float vv[8] = {a.x, a.y, a.z, a.w, c.x, c.y, c.z, c.w};
        #pragma unroll
        for (int j = 0; j < 8; ++j) { __bf16 hh = (__bf16)vv[j]; hi[j] = hh; lo[j] = (__bf16)(vv[j] - (float)hh); }
      } else {
        #pragma unroll
        for (int j = 0; j < 8; ++j) { hi[j] = (__bf16)0.f; lo[j] = (__bf16)0.f; }
      }
      kfh[ks][n] = hi; kfl[ks][n] = lo;
    }
  }
  // V fragments (B-operand: col -> d, k -> s), single bf16
  bf16x8 vf[3][4];
  #pragma unroll
  for (int ks = 0; ks < 3; ++ks) {
    #pragma unroll
    for (int n = 0; n < 4; ++n) {
      int d = col + 16*n;
      bf16x8 f;
      #pragma unroll
      for (int j = 0; j < 8; ++j) {
        int s = ks*32 + grp*8 + j;
        f[j] = (s < S_) ? (__bf16)V[((size_t)bh*S_ + s)*D_ + d] : (__bf16)0.f;
      }
      vf[ks][n] = f;
    }
  }

  for (int it = 0; it < 4; ++it) {
    const int lt = lchunk + it*64 + wid*16;
    // Q A-fragments (row=lane&15 -> l, k=(lane>>4)*8+j -> d), hi/lo split
    bf16x8 qh[2], ql[2];
    const float* qb = Q + ((size_t)bh*L_ + lt + col)*D_ + grp*8;
    #pragma unroll
    for (int ks = 0; ks < 2; ++ks) {
      const float4 a = *(const float4*)(qb + ks*32);
      const float4 c = *(const float4*)(qb + ks*32 + 4);
      float vv[8] = {a.x, a.y, a.z, a.w, c.x, c.y, c.z, c.w};
      #pragma unroll
      for (int j = 0; j < 8; ++j) { __bf16 hh = (__bf16)vv[j]; qh[ks][j] = hh; ql[ks][j] = (__bf16)(vv[j] - (float)hh); }
    }
    f32x4 acc[5];
    #pragma unroll
    for (int n = 0; n < 5; ++n) acc[n] = f32x4{0.f, 0.f, 0.f, 0.f};
    #pragma unroll
    for (int ks = 0; ks < 2; ++ks) {
      #pragma unroll
      for (int n = 0; n < 5; ++n) {
        acc[n] = __builtin_amdgcn_mfma_f32_16x16x32_bf16(qh[ks], kfh[ks][n], acc[n], 0, 0, 0);
        acc[n] = __builtin_amdgcn_mfma_f32_16x16x32_bf16(qh[ks], kfl[ks][n], acc[n], 0, 0, 0);
        acc[n] = __builtin_amdgcn_mfma_f32_16x16x32_bf16(ql[ks], kfh[ks][n], acc[n], 0, 0, 0);
      }
    }
    // scale 1/8 + mask s>=77
    #pragma unroll
    for (int n = 0; n < 5; ++n)
      #pragma unroll
      for (int r = 0; r < 4; ++r) acc[n][r] *= 0.125f;
    if (64 + col >= S_) {
      #pragma unroll
      for (int r = 0; r < 4; ++r) acc[4][r] = -1e30f;
    }
    // softmax over s (per row r: 5 local + 16-lane xor-reduce)
    float mx[4], sm[4];
    #pragma unroll
    for (int r = 0; r < 4; ++r) {
      float m0 = fmaxf(fmaxf(acc[0][r], acc[1][r]), fmaxf(acc[2][r], acc[3][r]));
      m0 = fmaxf(m0, acc[4][r]);
      #pragma unroll
      for (int s = 1; s < 16; s <<= 1) m0 = fmaxf(m0, __shfl_xor(m0, s, 64));
      mx[r] = m0;
    }
    #pragma unroll
    for (int n = 0; n < 5; ++n)
      #pragma unroll
      for (int r = 0; r < 4; ++r) acc[n][r] = __expf(acc[n][r] - mx[r]);
    #pragma unroll
    for (int r = 0; r < 4; ++r) {
      float s0 = acc[0][r] + acc[1][r] + acc[2][r] + acc[3][r] + acc[4][r];
      #pragma unroll
      for (int s = 1; s < 16; s <<= 1) s0 += __shfl_xor(s0, s, 64);
      sm[r] = __builtin_amdgcn_rcpf(s0);
    }
    // subject scales + write P tile (bf16)
    #pragma unroll
    for (int n = 0; n < 5; ++n) {
      const int s = 16*n + col;
      const float4 P = pp[s];
      const int a = pact[s];
      #pragma unroll
      for (int r = 0; r < 4; ++r) {
        float w = acc[n][r];
        if (a) {
          const int lg = lt + grp*4 + r;
          const float X = (float)(lg >> 6), Y = (float)(lg & 63);  // grid flat l = X*64 + Y
          w *= __expf(-((X - P.x)*(X - P.x)*P.z + (Y - P.y)*(Y - P.y)*P.w)) * invgv;
        }
        w *= sm[r];
        Wl[wid][grp*4 + r][s] = (__bf16)w;
      }
    }
    // PV: A-frag from LDS (row=lane&15, 8 contiguous s), B = vf
    f32x4 pacc[4];
    #pragma unroll
    for (int n = 0; n < 4; ++n) pacc[n] = f32x4{0.f, 0.f, 0.f, 0.f};
    #pragma unroll
    for (int ks = 0; ks < 3; ++ks) {
      const bf16x8 wf = *(const bf16x8*)&Wl[wid][col][ks*32 + grp*8];
      #pragma unroll
      for (int n = 0; n < 4; ++n)
        pacc[n] = __builtin_amdgcn_mfma_f32_16x16x32_bf16(wf, vf[ks][n], pacc[n], 0, 0, 0);
    }
    // store (4 x 64B segments per instr)
    float* ob = out + ((size_t)bh*L_ + lt + grp*4)*D_ + col;
    #pragma unroll
    for (int r = 0; r < 4; ++r)
      #pragma unroll
      for (int n = 0; n < 4; ++n) ob[(size_t)r*D_ + 16*n] = pacc[n][r];
  }
}

extern "C" void kernel_launch(void* const* d_in, const int* in_sizes, int n_in,
                              void* d_out, int out_size, void* d_ws, size_t ws_size,
                              hipStream_t stream) {
  const float* Q  = (const float*)d_in[0];
  const float* Kp = (const float*)d_in[1];
  const float* Vp = (const float*)d_in[2];
  const int* idxb = (const int*)d_in[3];
  const int* idxn = (const int*)d_in[4];
  float* out = (float*)d_out;

  char* w = (char*)d_ws;
  float* params = (float*)w;            // NP*8 floats
  float* invg = params + NP_*8;         // 1 float (+pad)
  int* pmap = (int*)(invg + 4);         // B*S ints
  size_t head = (size_t)(NP_*8 + 4)*sizeof(float) + (size_t)B_*S_*sizeof(int);
  head = (head + 255) & ~(size_t)255;
  float* subj;
  if (ws_size >= head + (size_t)NP_*L_*sizeof(float))
    subj = (float*)(w + head);
  else
    subj = out;  // fallback scratch: consumed by K2 before K3 overwrites d_out

  k1_subj<<<dim3(B_, L_/256), 256, 0, stream>>>(Q, Kp, idxb, idxn, subj);
  k2_moments<<<NP_, 256, 0, stream>>>(subj, params);
  k2b_finish<<<1, 256, 0, stream>>>(params, idxb, idxn, pmap, invg);
  k3_attn<<<dim3(L_/256, B_*H_), 256, 0, stream>>>(Q, Kp, Vp, pmap, params, invg, out);
}

// Round 2
// 173.651 us; speedup vs baseline: 1.9007x; 1.9007x over previous
//
#include <hip/hip_runtime.h>
#include <math.h>

#define B_ 16
#define H_ 10
#define L_ 4096
#define S_ 77
#define D_ 64
#define NE_ 20
#define NP_ (B_*NE_)
#define SHRINK_ 2.0f
#define LOG2E 1.4426950408889634f
#define SC_L2 (0.125f*LOG2E)

typedef __bf16 bf16x8 __attribute__((ext_vector_type(8)));
typedef float  f32x4  __attribute__((ext_vector_type(4)));

static __device__ __forceinline__ unsigned short bfb(__bf16 x) {
  return __builtin_bit_cast(unsigned short, x);
}
static __device__ __forceinline__ __bf16 mkbf(unsigned short x) {
  return __builtin_bit_cast(__bf16, x);
}

// ---------------- K1: subj[p=i*NE+j][l] = mean_h(Q[bs,h,l,:].K[bs,h,ss,:])/8 via MFMA ----
__global__ __launch_bounds__(256) void k1_subj(const float* __restrict__ Q,
                                               const float* __restrict__ K,
                                               const int* __restrict__ idxb,
                                               const int* __restrict__ idxn,
                                               float* __restrict__ subj) {
  __shared__ __bf16 KF[20][2][64][8];   // [ks][n][lane][j]  40 KB
  __shared__ float T[NE_][66];          // transpose tile for coalesced store
  __shared__ int bs[NE_], ss[NE_], s_uni;
  const int i = blockIdx.y, bx = blockIdx.x;
  const int tid = threadIdx.x, lane = tid & 63, wid = tid >> 6;
  const int c = lane & 15, g = lane >> 4;
  if (tid < NE_) { bs[tid] = idxb[i*NE_ + tid]; ss[tid] = idxn[i*NE_ + tid]; }
  __syncthreads();
  if (tid == 0) { int u = 1; for (int j = 1; j < NE_; ++j) u &= (bs[j] == bs[0]); s_uni = u; }
  // stage K fragments: j-slot 0..31 (>=20 zero), k4 0..159 (k = 0..639)
  for (int e4 = tid; e4 < 32*160; e4 += 256) {
    int j = e4 / 160, k = (e4 - j*160) * 4;
    float4 kv = make_float4(0.f, 0.f, 0.f, 0.f);
    if (j < NE_) kv = *(const float4*)&K[(((size_t)bs[j]*H_ + (k >> 6))*S_ + ss[j])*D_ + (k & 63)];
    int ks = k >> 5, gg = (k >> 3) & 3, jj = k & 7, n = j >> 4, cc = j & 15;
    uint2 pk;
    pk.x = (unsigned)bfb((__bf16)kv.x) | ((unsigned)bfb((__bf16)kv.y) << 16);
    pk.y = (unsigned)bfb((__bf16)kv.z) | ((unsigned)bfb((__bf16)kv.w) << 16);
    *(uint2*)&KF[ks][n][gg*16 + cc][jj] = pk;
  }
  __syncthreads();
  if (!s_uni) {
    // generic fallback (idx_b varies within a row): slow, correctness-only
    int ll = tid & 63, l = bx*64 + ll;
    for (int j = tid >> 6; j < NE_; j += 4) {
      float a = 0.f;
      for (int h = 0; h < H_; ++h) {
        const float* qp = Q + (((size_t)bs[j]*H_ + h)*L_ + l)*D_;
        const float* kp = K + (((size_t)bs[j]*H_ + h)*S_ + ss[j])*D_;
        for (int d = 0; d < 64; ++d) a += qp[d]*kp[d];
      }
      subj[(size_t)(i*NE_ + j)*L_ + l] = a * (1.0f/80.0f);
    }
    return;
  }
  {
    const int b0 = bs[0];
    const int lrow = bx*64 + wid*16 + c;
    f32x4 acc0 = {0.f,0.f,0.f,0.f}, acc1 = {0.f,0.f,0.f,0.f};
    #pragma unroll 4
    for (int ks = 0; ks < 20; ++ks) {
      const float* qp = Q + (((size_t)b0*H_ + (ks >> 1))*L_ + lrow)*D_ + (ks & 1)*32 + g*8;
      const float4 a = *(const float4*)qp;
      const float4 bq = *(const float4*)(qp + 4);
      bf16x8 af;
      af[0]=(__bf16)a.x;  af[1]=(__bf16)a.y;  af[2]=(__bf16)a.z;  af[3]=(__bf16)a.w;
      af[4]=(__bf16)bq.x; af[5]=(__bf16)bq.y; af[6]=(__bf16)bq.z; af[7]=(__bf16)bq.w;
      bf16x8 k0 = *(bf16x8*)&KF[ks][0][lane][0];
      bf16x8 k1 = *(bf16x8*)&KF[ks][1][lane][0];
      acc0 = __builtin_amdgcn_mfma_f32_16x16x32_bf16(af, k0, acc0, 0, 0, 0);
      acc1 = __builtin_amdgcn_mfma_f32_16x16x32_bf16(af, k1, acc1, 0, 0, 0);
    }
    const float sc = 1.0f/80.0f;
    #pragma unroll
    for (int r = 0; r < 4; ++r) {
      int ll = wid*16 + g*4 + r;
      T[c][ll] = acc0[r]*sc;                 // j = c (0..15)
      if (c < 4) T[16 + c][ll] = acc1[r]*sc; // j = 16..19
    }
  }
  __syncthreads();
  for (int e = tid; e < NE_*64; e += 256) {
    int j = e >> 6, ll = e & 63;
    subj[(size_t)(i*NE_ + j)*L_ + bx*64 + ll] = T[j][ll];
  }
}

// ---------------- K2: per-pair softmax over L + spatial moments -> 5 params ----------------
__global__ __launch_bounds__(256) void k2_moments(const float* __restrict__ subj,
                                                  float* __restrict__ params) {
  const int p = blockIdx.x;
  const int tid = threadIdx.x;
  const int lane = tid & 63, wid = tid >> 6;
  const float* sp = subj + (size_t)p*L_;
  __shared__ float red[4];
  float m = -1e30f;
  for (int l = tid; l < L_; l += 256) m = fmaxf(m, sp[l]);
  #pragma unroll
  for (int s = 1; s < 64; s <<= 1) m = fmaxf(m, __shfl_xor(m, s, 64));
  if (lane == 0) red[wid] = m;
  __syncthreads();
  m = fmaxf(fmaxf(red[0], red[1]), fmaxf(red[2], red[3]));
  __syncthreads();
  float se = 0, sy = 0, sx = 0, syy = 0, sxx = 0;
  for (int l = tid; l < L_; l += 256) {
    float e = __expf(sp[l] - m);
    float y = (float)(l >> 6), x = (float)(l & 63);
    se += e; sy += e*y; sx += e*x; syy += e*y*y; sxx += e*x*x;
  }
  float vals[5] = {se, sy, sx, syy, sxx};
  #pragma unroll
  for (int q = 0; q < 5; ++q) {
    float v = vals[q];
    #pragma unroll
    for (int s = 1; s < 64; s <<= 1) v += __shfl_xor(v, s, 64);
    if (lane == 0) red[wid] = v;
    __syncthreads();
    v = red[0] + red[1] + red[2] + red[3];
    __syncthreads();
    vals[q] = v;
  }
  if (tid == 0) {
    float xc = vals[2]/vals[0], yc = vals[1]/vals[0];
    float varx = vals[4]/vals[0] - xc*xc;
    float vary = vals[3]/vals[0] - yc*yc;
    float sh = SHRINK_ - 1.0f;
    float isx = sh*sh/(2.f*varx), isy = sh*sh/(2.f*vary);
    float rx = rintf(xc), ry = rintf(yc);
    float mv = __expf(-((rx-xc)*(rx-xc)*isx + (ry-yc)*(ry-yc)*isy));
    params[p*8+0] = xc; params[p*8+1] = yc;
    params[p*8+2] = isx; params[p*8+3] = isy; params[p*8+4] = mv;
  }
}

// ---------------- K2b: global grid max (as log2) + (b,s) -> pair map ----------------
__global__ __launch_bounds__(256) void k2b_finish(const float* __restrict__ params,
                                                  const int* __restrict__ idxb,
                                                  const int* __restrict__ idxn,
                                                  int* __restrict__ pmap,
                                                  float* __restrict__ l2invg) {
  const int tid = threadIdx.x;
  for (int e = tid; e < B_*S_; e += 256) pmap[e] = -1;
  __syncthreads();
  for (int p = tid; p < NP_; p += 256) pmap[idxb[p]*S_ + idxn[p]] = p;
  float m = 0.f;
  for (int p = tid; p < NP_; p += 256) m = fmaxf(m, params[p*8+4]);
  #pragma unroll
  for (int s = 1; s < 64; s <<= 1) m = fmaxf(m, __shfl_xor(m, s, 64));
  __shared__ float red[4];
  if ((tid & 63) == 0) red[tid >> 6] = m;
  __syncthreads();
  if (tid == 0) {
    m = fmaxf(fmaxf(red[0], red[1]), fmaxf(red[2], red[3]));
    l2invg[0] = -log2f(m);
  }
}

// ---------------- K3: fused attention: softmax(QK^T/8) * scales @ V ----------------
__global__ __launch_bounds__(256, 4) void k3_attn(const float* __restrict__ Q,
                                                  const float* __restrict__ K,
                                                  const float* __restrict__ V,
                                                  const int* __restrict__ pmap,
                                                  const float* __restrict__ params,
                                                  const float* __restrict__ l2invg,
                                                  float* __restrict__ out) {
  __shared__ __bf16 KF[2][5][64][8];   // 10.25 KB  [ks][n][lane][j]: K[s=16n+c][d=32ks+8g+j]
  __shared__ __bf16 VF[3][4][64][8];   // 12 KB     [ks][n][lane][j]: V[s=32ks+8g+j][d=16n+c]
  __shared__ __bf16 Wl[4][16][120];    // 15 KB     per-wave P tile (cols 80..95 zeroed)
  __shared__ float4 pp[80];            // per-s gaussian params (yc, -isy*log2e, C, 0)

  const int bh = blockIdx.y, b = bh / H_, bx = blockIdx.x;
  const int tid = threadIdx.x, lane = tid & 63, wid = tid >> 6;
  const int c = lane & 15, g = lane >> 4;
  const int lt = bx*64 + wid*16;

  // issue Q loads early (A-frag: row c -> l, k = 32ks + 8g + j)
  const float* qbase = Q + ((size_t)bh*L_ + lt + c)*D_ + g*8;
  const float4 qa0 = *(const float4*)(qbase);
  const float4 qa1 = *(const float4*)(qbase + 4);
  const float4 qc0 = *(const float4*)(qbase + 32);
  const float4 qc1 = *(const float4*)(qbase + 36);

  // zero P pad cols 80..95 (read by PV ks=2, never written)
  *(uint2*)&Wl[wid][c][80 + g*4] = make_uint2(0u, 0u);

  // stage K fragments (RNE bf16, hi only)
  for (int e4 = tid; e4 < 80*16; e4 += 256) {
    int s = e4 >> 4, d = (e4 & 15) * 4;
    float4 kv = make_float4(0.f, 0.f, 0.f, 0.f);
    if (s < S_) kv = *(const float4*)&K[((size_t)bh*S_ + s)*D_ + d];
    int n = s >> 4, cc = s & 15, ks = d >> 5, gg = (d >> 3) & 3, jj = d & 7;
    uint2 pk;
    pk.x = (unsigned)bfb((__bf16)kv.x) | ((unsigned)bfb((__bf16)kv.y) << 16);
    pk.y = (unsigned)bfb((__bf16)kv.z) | ((unsigned)bfb((__bf16)kv.w) << 16);
    *(uint2*)&KF[ks][n][gg*16 + cc][jj] = pk;
  }
  // stage V fragments
  for (int e4 = tid; e4 < 80*16; e4 += 256) {
    int s = e4 >> 4, d = (e4 & 15) * 4;
    float4 vv = make_float4(0.f, 0.f, 0.f, 0.f);
    if (s < S_) vv = *(const float4*)&V[((size_t)bh*S_ + s)*D_ + d];
    int ks = s >> 5, gg = (s >> 3) & 3, jj = s & 7;
    int n0 = d >> 4, c0 = d & 15;
    VF[ks][n0][gg*16 + c0 + 0][jj] = (__bf16)vv.x;
    VF[ks][n0][gg*16 + c0 + 1][jj] = (__bf16)vv.y;
    VF[ks][n0][gg*16 + c0 + 2][jj] = (__bf16)vv.z;
    VF[ks][n0][gg*16 + c0 + 3][jj] = (__bf16)vv.w;
  }
  // per-s gaussian params; X = l>>6 = bx is block-constant
  for (int s = tid; s < 80; s += 256) {
    float4 v = make_float4(0.f, 0.f, 0.f, 0.f);
    if (s < S_) {
      int pid = pmap[b*S_ + s];
      if (pid >= 0) {
        float xc = params[pid*8+0], yc = params[pid*8+1];
        float isx = params[pid*8+2], isy = params[pid*8+3];
        float X = (float)bx;
        float A = (X - xc)*(X - xc)*isx;
        v.x = yc; v.y = -isy*LOG2E; v.z = l2invg[0] - A*LOG2E;
      }
    }
    pp[s] = v;
  }
  __syncthreads();

  // Q hi/lo split (truncation split: hi = top 16 bits, lo = RNE of remainder)
  bf16x8 qh[2], ql[2];
  {
    float vv0[8] = {qa0.x, qa0.y, qa0.z, qa0.w, qa1.x, qa1.y, qa1.z, qa1.w};
    float vv1[8] = {qc0.x, qc0.y, qc0.z, qc0.w, qc1.x, qc1.y, qc1.z, qc1.w};
    #pragma unroll
    for (int j = 0; j < 8; ++j) {
      unsigned u0 = __float_as_uint(vv0[j]);
      qh[0][j] = mkbf((unsigned short)(u0 >> 16));
      ql[0][j] = (__bf16)(vv0[j] - __uint_as_float(u0 & 0xffff0000u));
      unsigned u1 = __float_as_uint(vv1[j]);
      qh[1][j] = mkbf((unsigned short)(u1 >> 16));
      ql[1][j] = (__bf16)(vv1[j] - __uint_as_float(u1 & 0xffff0000u));
    }
  }

  // QK^T: acc[n] covers s = 16n + c; rows l = lt + 4g + r
  f32x4 acc[5];
  #pragma unroll
  for (int n = 0; n < 5; ++n) acc[n] = f32x4{0.f, 0.f, 0.f, 0.f};
  #pragma unroll
  for (int ks = 0; ks < 2; ++ks) {
    #pragma unroll
    for (int n = 0; n < 5; ++n) {
      bf16x8 kf = *(bf16x8*)&KF[ks][n][lane][0];
      acc[n] = __builtin_amdgcn_mfma_f32_16x16x32_bf16(qh[ks], kf, acc[n], 0, 0, 0);
      acc[n] = __builtin_amdgcn_mfma_f32_16x16x32_bf16(ql[ks], kf, acc[n], 0, 0, 0);
    }
  }
  // scale to log2 domain + mask s >= 77
  #pragma unroll
  for (int n = 0; n < 5; ++n)
    #pragma unroll
    for (int r = 0; r < 4; ++r) acc[n][r] *= SC_L2;
  if (c >= 13) {
    #pragma unroll
    for (int r = 0; r < 4; ++r) acc[4][r] = -1e30f;
  }
  // row softmax (rows r, reduce across 16 lanes)
  float mx[4], sm[4];
  #pragma unroll
  for (int r = 0; r < 4; ++r) {
    float m0 = fmaxf(fmaxf(acc[0][r], acc[1][r]), fmaxf(acc[2][r], acc[3][r]));
    m0 = fmaxf(m0, acc[4][r]);
    #pragma unroll
    for (int s = 1; s < 16; s <<= 1) m0 = fmaxf(m0, __shfl_xor(m0, s, 64));
    mx[r] = m0;
  }
  #pragma unroll
  for (int n = 0; n < 5; ++n)
    #pragma unroll
    for (int r = 0; r < 4; ++r) acc[n][r] = __builtin_amdgcn_exp2f(acc[n][r] - mx[r]);
  #pragma unroll
  for (int r = 0; r < 4; ++r) {
    float s0 = acc[0][r] + acc[1][r] + acc[2][r] + acc[3][r] + acc[4][r];
    #pragma unroll
    for (int s = 1; s < 16; s <<= 1) s0 += __shfl_xor(s0, s, 64);
    sm[r] = __builtin_amdgcn_rcpf(s0);
  }
  // apply gaussian scales (branchless) + write P tile
  float Yr[4];
  #pragma unroll
  for (int r = 0; r < 4; ++r) Yr[r] = (float)(wid*16 + g*4 + r);
  #pragma unroll
  for (int n = 0; n < 5; ++n) {
    const float4 sp4 = pp[16*n + c];
    #pragma unroll
    for (int r = 0; r < 4; ++r) {
      float t = Yr[r] - sp4.x;
      float gm = __builtin_amdgcn_exp2f(fmaf(t*t, sp4.y, sp4.z));
      float w = acc[n][r] * gm * sm[r];
      Wl[wid][g*4 + r][16*n + c] = (__bf16)w;
    }
  }
  // PV
  f32x4 pacc[4];
  #pragma unroll
  for (int n = 0; n < 4; ++n) pacc[n] = f32x4{0.f, 0.f, 0.f, 0.f};
  #pragma unroll
  for (int ks = 0; ks < 3; ++ks) {
    bf16x8 wf = *(bf16x8*)&Wl[wid][c][ks*32 + g*8];
    #pragma unroll
    for (int n = 0; n < 4; ++n) {
      bf16x8 vf = *(bf16x8*)&VF[ks][n][lane][0];
      pacc[n] = __builtin_amdgcn_mfma_f32_16x16x32_bf16(wf, vf, pacc[n], 0, 0, 0);
    }
  }
  // store: per (r,n) 64 lanes cover 4 rows x 64B segments
  float* ob = out + ((size_t)bh*L_ + lt + g*4)*D_ + c;
  #pragma unroll
  for (int r = 0; r < 4; ++r)
    #pragma unroll
    for (int n = 0; n < 4; ++n) ob[(size_t)r*D_ + 16*n] = pacc[n][r];
}

extern "C" void kernel_launch(void* const* d_in, const int* in_sizes, int n_in,
                              void* d_out, int out_size, void* d_ws, size_t ws_size,
                              hipStream_t stream) {
  const float* Q  = (const float*)d_in[0];
  const float* Kp = (const float*)d_in[1];
  const float* Vp = (const float*)d_in[2];
  const int* idxb = (const int*)d_in[3];
  const int* idxn = (const int*)d_in[4];
  float* out = (float*)d_out;

  char* w = (char*)d_ws;
  float* params = (float*)w;            // NP*8 floats
  float* l2invg = params + NP_*8;       // 1 float (+pad)
  int* pmap = (int*)(l2invg + 4);       // B*S ints
  size_t head = (size_t)(NP_*8 + 4)*sizeof(float) + (size_t)B_*S_*sizeof(int);
  head = (head + 255) & ~(size_t)255;
  float* subj;
  if (ws_size >= head + (size_t)NP_*L_*sizeof(float))
    subj = (float*)(w + head);
  else
    subj = out;  // fallback scratch: consumed by K2 before K3 overwrites d_out

  k1_subj<<<dim3(L_/64, B_), 256, 0, stream>>>(Q, Kp, idxb, idxn, subj);
  k2_moments<<<NP_, 256, 0, stream>>>(subj, params);
  k2b_finish<<<1, 256, 0, stream>>>(params, idxb, idxn, pmap, l2invg);
  k3_attn<<<dim3(L_/64, B_*H_), 256, 0, stream>>>(Q, Kp, Vp, pmap, params, l2invg, out);
}